// Round 1
// baseline (291.185 us; speedup 1.0000x reference)
//
#include <hip/hip_runtime.h>
#include <stdint.h>

#define AS1 __attribute__((address_space(1)))
#define AS3 __attribute__((address_space(3)))

typedef __bf16 bf16_t;
typedef bf16_t bf16x8 __attribute__((ext_vector_type(8)));
typedef float  f32x4  __attribute__((ext_vector_type(4)));
typedef unsigned short u16;

constexpr int D     = 1280;
constexpr int H     = 20;
constexpr int HD    = 64;
constexpr int NQ    = 1600;
constexpr int NKV   = 6000;
constexpr int ENC   = 1500;
constexpr int QPAD  = 1632;   // NQ padded so q-row reads past the end stay in-buffer
constexpr int KVP   = 1504;   // per-request kv rows padded to 16 (keeps 16B-aligned frags)
constexpr int KVTOT = 4 * KVP;

__device__ __forceinline__ u16 f2bf(float f) {
  union { float f; uint32_t u; } x; x.f = f;
  uint32_t r = (x.u + 0x7fffu + ((x.u >> 16) & 1u)) >> 16;  // RNE
  return (u16)r;
}

__device__ __forceinline__ void gload16(const void* g, void* l) {
  __builtin_amdgcn_global_load_lds((AS1 void*)g, (AS3 void*)l, 16, 0, 0);
}

// ---------------- fp32 -> bf16 elementwise (vectorized) ----------------
__global__ __launch_bounds__(256)
void cvt_kernel(const float* __restrict__ in, u16* __restrict__ out, int n4) {
  int i = blockIdx.x * 256 + threadIdx.x;
  if (i >= n4) return;
  float4 v = ((const float4*)in)[i];
  ushort4 o;
  o.x = f2bf(v.x); o.y = f2bf(v.y); o.z = f2bf(v.z); o.w = f2bf(v.w);
  ((ushort4*)out)[i] = o;
}

// ---------------- fp32 [R][C] -> bf16 [C][R] tiled transpose ----------------
__global__ __launch_bounds__(256)
void tpose_kernel(const float* __restrict__ in, u16* __restrict__ out, int R, int C) {
  __shared__ u16 tile[32][33];
  int bc = blockIdx.x * 32, br = blockIdx.y * 32;
  int tx = threadIdx.x & 31, ty = threadIdx.x >> 5;  // 32 x 8
#pragma unroll
  for (int i = 0; i < 32; i += 8)
    tile[ty + i][tx] = f2bf(in[(size_t)(br + ty + i) * C + bc + tx]);
  __syncthreads();
#pragma unroll
  for (int i = 0; i < 32; i += 8)
    out[(size_t)(bc + ty + i) * R + br + tx] = tile[tx][ty + i];
}

// ---------------- bf16 GEMM: C[M,N] = A[M,1280] @ Bt[N,1280]^T + bias ----------------
// MODE 0: Q-proj  -> qh[h][row][hd] = (c+b)*0.125          (bf16)
// MODE 1: KV-proj -> kh[h][req*KVP+loc][hd] / vt[h][hd][req*KVP+loc]  (bf16)
// MODE 2: O-proj  -> outF[row*1280+col] = c+b               (fp32)
template <int MODE>
__global__ __launch_bounds__(256)
void gemm_kernel(const u16* __restrict__ A, const u16* __restrict__ Bt,
                 const float* __restrict__ bias, int M,
                 u16* __restrict__ outA, u16* __restrict__ outB, float* __restrict__ outF) {
  __shared__ __align__(16) u16 As[128 * 64];
  __shared__ __align__(16) u16 Bs[128 * 64];
  const int tid = threadIdx.x;
  const int lane = tid & 63, l15 = lane & 15, lg = lane >> 4;
  const int w = tid >> 6, wr = w >> 1, wc = w & 1;
  const int m0 = blockIdx.y * 128, n0 = blockIdx.x * 128;

  f32x4 acc[4][4] = {};

  for (int k0 = 0; k0 < D; k0 += 64) {
    // stage A tile [128 rows][64 k] bf16, XOR-swizzled (pre-swizzled global source,
    // linear LDS dest as global_load_lds requires; read side applies same XOR)
#pragma unroll
    for (int p = 0; p < 4; ++p) {
      int off = p * 4096 + tid * 16;
      int lg_off = off ^ (((off >> 7) & 7) << 4);
      int row = lg_off >> 7, kb = lg_off & 127;
      int gr = m0 + row; gr = gr < M ? gr : M - 1;  // clamp M-tail
      gload16((const char*)A + ((size_t)gr * D + k0) * 2 + kb, (char*)As + off);
    }
#pragma unroll
    for (int p = 0; p < 4; ++p) {
      int off = p * 4096 + tid * 16;
      int lg_off = off ^ (((off >> 7) & 7) << 4);
      int row = lg_off >> 7, kb = lg_off & 127;
      int gr = n0 + row;  // N is always a multiple of 128
      gload16((const char*)Bt + ((size_t)gr * D + k0) * 2 + kb, (char*)Bs + off);
    }
    __syncthreads();
#pragma unroll
    for (int kk = 0; kk < 2; ++kk) {
      const int kbyte = kk * 64 + lg * 16;
      bf16x8 af[4], bfr[4];
#pragma unroll
      for (int m = 0; m < 4; ++m) {
        int row = wr * 64 + m * 16 + l15;
        int addr = ((row << 7) + kbyte) ^ ((row & 7) << 4);
        af[m] = *(const bf16x8*)((const char*)As + addr);
      }
#pragma unroll
      for (int n = 0; n < 4; ++n) {
        int row = wc * 64 + n * 16 + l15;
        int addr = ((row << 7) + kbyte) ^ ((row & 7) << 4);
        bfr[n] = *(const bf16x8*)((const char*)Bs + addr);
      }
#pragma unroll
      for (int m = 0; m < 4; ++m)
#pragma unroll
        for (int n = 0; n < 4; ++n)
          acc[m][n] = __builtin_amdgcn_mfma_f32_16x16x32_bf16(af[m], bfr[n], acc[m][n], 0, 0, 0);
    }
    __syncthreads();
  }

  // epilogue: C/D layout col = lane&15, row = (lane>>4)*4 + reg  [m89-verified]
#pragma unroll
  for (int m = 0; m < 4; ++m)
#pragma unroll
    for (int n = 0; n < 4; ++n) {
      int col = n0 + wc * 64 + n * 16 + l15;
      float bv = bias[col];
#pragma unroll
      for (int r = 0; r < 4; ++r) {
        int row = m0 + wr * 64 + m * 16 + lg * 4 + r;
        if (row >= M) continue;
        float v = acc[m][n][r] + bv;
        if (MODE == 0) {
          v *= 0.125f;  // HD^-0.5
          int h = col >> 6, hd = col & 63;
          outA[((size_t)(h * QPAD + row)) * HD + hd] = f2bf(v);
        } else if (MODE == 1) {
          int req = row / ENC, loc = row - req * ENC;
          int rr = req * KVP + loc;
          if (col < D) {
            int h = col >> 6, hd = col & 63;
            outA[((size_t)(h * KVTOT + rr)) * HD + hd] = f2bf(v);
          } else {
            int c2 = col - D, h = c2 >> 6, hd = c2 & 63;
            outB[((size_t)(h * HD + hd)) * KVTOT + rr] = f2bf(v);
          }
        } else {
          outF[(size_t)row * D + col] = v;
        }
      }
    }
}

// ---------------- flash attention: 1 wave = 16 q rows, kv steps of 32 ----------------
__global__ __launch_bounds__(256)
void attn_kernel(const u16* __restrict__ qh, const u16* __restrict__ kh,
                 const u16* __restrict__ vt, const int* __restrict__ seq,
                 u16* __restrict__ attnb) {
  __shared__ __align__(16) u16 Pbuf[4][512];  // per-wave 16x32 bf16 P transpose buffer
  const int lane = threadIdx.x & 63, l15 = lane & 15, lg = lane >> 4;
  const int w = threadIdx.x >> 6;
  const int head = blockIdx.z, req = blockIdx.y;
  int s0 = seq[0], s1 = seq[1], s2 = seq[2];
  int qstart = (req > 0 ? s0 : 0) + (req > 1 ? s1 : 0) + (req > 2 ? s2 : 0);
  int slen = seq[req];
  int q0 = blockIdx.x * 64 + w * 16;
  if (q0 >= slen) return;  // no __syncthreads in this kernel -> early exit is safe

  // hoist Q fragments (A-frag: row = lane&15, k = (lane>>4)*8+e)
  const u16* qrow = qh + ((size_t)(head * QPAD + qstart + q0 + l15)) * HD + lg * 8;
  bf16x8 qa0 = *(const bf16x8*)qrow;
  bf16x8 qa1 = *(const bf16x8*)(qrow + 32);

  f32x4 o[4] = {};
  float mx[4], ls[4] = {0.f, 0.f, 0.f, 0.f};
#pragma unroll
  for (int r = 0; r < 4; ++r) mx[r] = -__builtin_inff();

  const u16* kbase = kh + ((size_t)(head * KVTOT + req * KVP)) * HD;
  const u16* vbase = vt + ((size_t)(head * HD)) * KVTOT + req * KVP;
  const float C = 1.44269504088896340736f;

  for (int kt = 0; kt < 47; ++kt) {  // ceil(1500/32)
    int kvb = kt * 32;
    f32x4 s[2];
#pragma unroll
    for (int n = 0; n < 2; ++n) {
      const u16* kr = kbase + (size_t)(kvb + n * 16 + l15) * HD + lg * 8;
      bf16x8 kb0 = *(const bf16x8*)kr;
      bf16x8 kb1 = *(const bf16x8*)(kr + 32);
      f32x4 z = {};
      z = __builtin_amdgcn_mfma_f32_16x16x32_bf16(qa0, kb0, z, 0, 0, 0);
      s[n] = __builtin_amdgcn_mfma_f32_16x16x32_bf16(qa1, kb1, s[n] = z, 0, 0, 0);
    }
    if (kt == 46) {  // mask kv >= 1500 (pad rows)
#pragma unroll
      for (int n = 0; n < 2; ++n)
        if (kvb + n * 16 + l15 >= ENC) {
#pragma unroll
          for (int r = 0; r < 4; ++r) s[n][r] = -__builtin_inff();
        }
    }
#pragma unroll
    for (int r = 0; r < 4; ++r) {
      float v = fmaxf(s[0][r], s[1][r]);
      v = fmaxf(v, __shfl_xor(v, 1));
      v = fmaxf(v, __shfl_xor(v, 2));
      v = fmaxf(v, __shfl_xor(v, 4));
      v = fmaxf(v, __shfl_xor(v, 8));
      float mnew = fmaxf(mx[r], v);
      float sc = exp2f((mx[r] - mnew) * C);
      mx[r] = mnew;
      float p0 = exp2f((s[0][r] - mnew) * C);
      float p1 = exp2f((s[1][r] - mnew) * C);
      ls[r] = ls[r] * sc + p0 + p1;
      o[0][r] *= sc; o[1][r] *= sc; o[2][r] *= sc; o[3][r] *= sc;
      int prow = lg * 4 + r;
      Pbuf[w][prow * 32 + l15] = f2bf(p0);
      Pbuf[w][prow * 32 + 16 + l15] = f2bf(p1);
    }
    // same-wave LDS transpose: P (C-layout) -> A-frag
    bf16x8 pa = *(const bf16x8*)&Pbuf[w][l15 * 32 + lg * 8];
#pragma unroll
    for (int dt = 0; dt < 4; ++dt) {
      const u16* vr = vbase + (size_t)(dt * 16 + l15) * KVTOT + kvb + lg * 8;
      bf16x8 vb = *(const bf16x8*)vr;
      o[dt] = __builtin_amdgcn_mfma_f32_16x16x32_bf16(pa, vb, o[dt], 0, 0, 0);
    }
  }
#pragma unroll
  for (int r = 0; r < 4; ++r) {
    float v = ls[r];
    v += __shfl_xor(v, 1);
    v += __shfl_xor(v, 2);
    v += __shfl_xor(v, 4);
    v += __shfl_xor(v, 8);
    ls[r] = 1.0f / v;
  }
#pragma unroll
  for (int dt = 0; dt < 4; ++dt)
#pragma unroll
    for (int r = 0; r < 4; ++r) {
      int qr = q0 + lg * 4 + r;
      if (qr < slen)
        attnb[(size_t)(qstart + qr) * D + head * HD + dt * 16 + l15] = f2bf(o[dt][r] * ls[r]);
    }
}

extern "C" void kernel_launch(void* const* d_in, const int* in_sizes, int n_in,
                              void* d_out, int out_size, void* d_ws, size_t ws_size,
                              hipStream_t stream) {
  const float* hs  = (const float*)d_in[0];
  const float* chs = (const float*)d_in[1];
  const int*   seq = (const int*)d_in[2];
  const float* Wq  = (const float*)d_in[3];
  const float* bq  = (const float*)d_in[4];
  const float* Wkv = (const float*)d_in[5];
  const float* bkv = (const float*)d_in[6];
  const float* Wo  = (const float*)d_in[7];
  const float* bo  = (const float*)d_in[8];

  char* ws = (char*)d_ws;
  u16* hsb   = (u16*)(ws + 0);          // 1600*1280*2  = 4,096,000
  u16* chsb  = (u16*)(ws + 4096000);    // 6000*1280*2  = 15,360,000
  u16* Wqt   = (u16*)(ws + 19456000);   // 1280*1280*2  = 3,276,800
  u16* Wkvt  = (u16*)(ws + 22732800);   // 2560*1280*2  = 6,553,600
  u16* Wot   = (u16*)(ws + 29286400);   // 3,276,800
  u16* qhb   = (u16*)(ws + 32563200);   // 20*1632*64*2 = 4,177,920
  u16* khb   = (u16*)(ws + 36741120);   // 20*6016*64*2 = 15,400,960
  u16* vtb   = (u16*)(ws + 52142080);   // 15,400,960
  u16* attnb = (u16*)(ws + 67543040);   // 4,096,000  -> total 71,639,040 B

  cvt_kernel<<<2000, 256, 0, stream>>>(hs, hsb, 512000);
  cvt_kernel<<<7500, 256, 0, stream>>>(chs, chsb, 1920000);
  tpose_kernel<<<dim3(40, 40), 256, 0, stream>>>(Wq, Wqt, 1280, 1280);
  tpose_kernel<<<dim3(80, 40), 256, 0, stream>>>(Wkv, Wkvt, 1280, 2560);
  tpose_kernel<<<dim3(40, 40), 256, 0, stream>>>(Wo, Wot, 1280, 1280);

  gemm_kernel<0><<<dim3(10, 13), 256, 0, stream>>>(hsb, Wqt, bq, NQ, qhb, nullptr, nullptr);
  gemm_kernel<1><<<dim3(20, 47), 256, 0, stream>>>(chsb, Wkvt, bkv, NKV, khb, vtb, nullptr);
  attn_kernel<<<dim3(8, 4, 20), 256, 0, stream>>>(qhb, khb, vtb, seq, attnb);
  gemm_kernel<2><<<dim3(10, 13), 256, 0, stream>>>(attnb, Wot, bo, NQ, nullptr, nullptr, (float*)d_out);
}

// Round 2
// 285.770 us; speedup vs baseline: 1.0189x; 1.0189x over previous
//
#include <hip/hip_runtime.h>
#include <stdint.h>

#define AS1 __attribute__((address_space(1)))
#define AS3 __attribute__((address_space(3)))

typedef __bf16 bf16_t;
typedef bf16_t bf16x8 __attribute__((ext_vector_type(8)));
typedef float  f32x4  __attribute__((ext_vector_type(4)));
typedef unsigned short u16;

constexpr int D     = 1280;
constexpr int H     = 20;
constexpr int HD    = 64;
constexpr int NQ    = 1600;
constexpr int NKV   = 6000;
constexpr int ENC   = 1500;
constexpr int QPAD  = 1632;   // NQ padded so q-row reads past the end stay in-buffer
constexpr int KVP   = 1504;   // per-request kv rows padded to 16 (keeps 16B-aligned frags)
constexpr int KVTOT = 4 * KVP;

__device__ __forceinline__ u16 f2bf(float f) {
  union { float f; uint32_t u; } x; x.f = f;
  uint32_t r = (x.u + 0x7fffu + ((x.u >> 16) & 1u)) >> 16;  // RNE
  return (u16)r;
}

__device__ __forceinline__ void gload16(const void* g, void* l) {
  __builtin_amdgcn_global_load_lds((AS1 void*)g, (AS3 void*)l, 16, 0, 0);
}

// ---------------- fp32 -> bf16 elementwise (vectorized) ----------------
__global__ __launch_bounds__(256)
void cvt_kernel(const float* __restrict__ in, u16* __restrict__ out, int n4) {
  int i = blockIdx.x * 256 + threadIdx.x;
  if (i >= n4) return;
  float4 v = ((const float4*)in)[i];
  ushort4 o;
  o.x = f2bf(v.x); o.y = f2bf(v.y); o.z = f2bf(v.z); o.w = f2bf(v.w);
  ((ushort4*)out)[i] = o;
}

// ---------------- fp32 [R][C] -> bf16 [C][R] tiled transpose ----------------
__global__ __launch_bounds__(256)
void tpose_kernel(const float* __restrict__ in, u16* __restrict__ out, int R, int C) {
  __shared__ u16 tile[32][33];
  int bc = blockIdx.x * 32, br = blockIdx.y * 32;
  int tx = threadIdx.x & 31, ty = threadIdx.x >> 5;  // 32 x 8
#pragma unroll
  for (int i = 0; i < 32; i += 8)
    tile[ty + i][tx] = f2bf(in[(size_t)(br + ty + i) * C + bc + tx]);
  __syncthreads();
#pragma unroll
  for (int i = 0; i < 32; i += 8)
    out[(size_t)(bc + ty + i) * R + br + tx] = tile[tx][ty + i];
}

// ---------------- bf16 GEMM: C[M,N] = A[M,1280] @ Bt[N,1280]^T + bias ----------------
// MODE 0: Q-proj  -> qh[h][row][hd] = (c+b)*0.125          (bf16)
// MODE 1: KV-proj -> kh[h][req*KVP+loc][hd] / vt[h][hd][req*KVP+loc]  (bf16)
// MODE 2: O-proj  -> outF[row*1280+col] = c+b               (fp32)
template <int MODE>
__global__ __launch_bounds__(256)
void gemm_kernel(const u16* __restrict__ A, const u16* __restrict__ Bt,
                 const float* __restrict__ bias, int M,
                 u16* __restrict__ outA, u16* __restrict__ outB, float* __restrict__ outF) {
  __shared__ __align__(16) u16 As[128 * 64];
  __shared__ __align__(16) u16 Bs[128 * 64];
  const int tid = threadIdx.x;
  const int lane = tid & 63, l15 = lane & 15, lg = lane >> 4;
  const int w = tid >> 6, wr = w >> 1, wc = w & 1;
  const int m0 = blockIdx.y * 128, n0 = blockIdx.x * 128;

  f32x4 acc[4][4] = {};

  for (int k0 = 0; k0 < D; k0 += 64) {
    // stage A tile [128 rows][64 k] bf16, XOR-swizzled (pre-swizzled global source,
    // linear LDS dest as global_load_lds requires; read side applies same XOR)
#pragma unroll
    for (int p = 0; p < 4; ++p) {
      int off = p * 4096 + tid * 16;
      int lg_off = off ^ (((off >> 7) & 7) << 4);
      int row = lg_off >> 7, kb = lg_off & 127;
      int gr = m0 + row; gr = gr < M ? gr : M - 1;  // clamp M-tail
      gload16((const char*)A + ((size_t)gr * D + k0) * 2 + kb, (char*)As + off);
    }
#pragma unroll
    for (int p = 0; p < 4; ++p) {
      int off = p * 4096 + tid * 16;
      int lg_off = off ^ (((off >> 7) & 7) << 4);
      int row = lg_off >> 7, kb = lg_off & 127;
      int gr = n0 + row;  // N is always a multiple of 128
      gload16((const char*)Bt + ((size_t)gr * D + k0) * 2 + kb, (char*)Bs + off);
    }
    __syncthreads();
#pragma unroll
    for (int kk = 0; kk < 2; ++kk) {
      const int kbyte = kk * 64 + lg * 16;
      bf16x8 af[4], bfr[4];
#pragma unroll
      for (int m = 0; m < 4; ++m) {
        int row = wr * 64 + m * 16 + l15;
        int addr = ((row << 7) + kbyte) ^ ((row & 7) << 4);
        af[m] = *(const bf16x8*)((const char*)As + addr);
      }
#pragma unroll
      for (int n = 0; n < 4; ++n) {
        int row = wc * 64 + n * 16 + l15;
        int addr = ((row << 7) + kbyte) ^ ((row & 7) << 4);
        bfr[n] = *(const bf16x8*)((const char*)Bs + addr);
      }
#pragma unroll
      for (int m = 0; m < 4; ++m)
#pragma unroll
        for (int n = 0; n < 4; ++n)
          acc[m][n] = __builtin_amdgcn_mfma_f32_16x16x32_bf16(af[m], bfr[n], acc[m][n], 0, 0, 0);
    }
    __syncthreads();
  }

  // epilogue: C/D layout col = lane&15, row = (lane>>4)*4 + reg  [m89-verified]
#pragma unroll
  for (int m = 0; m < 4; ++m)
#pragma unroll
    for (int n = 0; n < 4; ++n) {
      int col = n0 + wc * 64 + n * 16 + l15;
      float bv = bias[col];
#pragma unroll
      for (int r = 0; r < 4; ++r) {
        int row = m0 + wr * 64 + m * 16 + lg * 4 + r;
        if (row >= M) continue;
        float v = acc[m][n][r] + bv;
        if (MODE == 0) {
          v *= 0.125f;  // HD^-0.5
          int h = col >> 6, hd = col & 63;
          outA[((size_t)(h * QPAD + row)) * HD + hd] = f2bf(v);
        } else if (MODE == 1) {
          int req = row / ENC, loc = row - req * ENC;
          int rr = req * KVP + loc;
          if (col < D) {
            int h = col >> 6, hd = col & 63;
            outA[((size_t)(h * KVTOT + rr)) * HD + hd] = f2bf(v);
          } else {
            int c2 = col - D, h = c2 >> 6, hd = c2 & 63;
            outB[((size_t)(h * HD + hd)) * KVTOT + rr] = f2bf(v);
          }
        } else {
          outF[(size_t)row * D + col] = v;
        }
      }
    }
}

// ---------------- flash attention, in-block KV-split ----------------
// Block = (q16-tile, req, head); 4 waves each take a KV quarter (384/384/384/348),
// partials (m, l, o) combined through LDS in f32 at the end.
__global__ __launch_bounds__(256, 8)
void attn_kernel(const u16* __restrict__ qh, const u16* __restrict__ kh,
                 const u16* __restrict__ vt, const int* __restrict__ seq,
                 u16* __restrict__ attnb) {
  // per-wave region: [0..1024) floats = Ocmb 16x64 (Pbuf 16x32 bf16 overlays first 256),
  // [1024..1040) = m_w per row, [1040..1056) = l_w per row; stride 1088 floats.
  __shared__ __align__(16) float smem[4][1088];
  const int lane = threadIdx.x & 63, l15 = lane & 15, lg = lane >> 4;
  const int w = threadIdx.x >> 6;
  const int head = blockIdx.z, req = blockIdx.y;
  int s0 = seq[0], s1 = seq[1], s2 = seq[2];
  int qstart = (req > 0 ? s0 : 0) + (req > 1 ? s1 : 0) + (req > 2 ? s2 : 0);
  int slen = seq[req];
  int q0 = blockIdx.x * 16;
  if (q0 >= slen) return;  // uniform across block: no thread reaches __syncthreads

  // hoist Q fragments (A-frag: row = lane&15, k = (lane>>4)*8+e)
  const u16* qrow = qh + ((size_t)(head * QPAD + qstart + q0 + l15)) * HD + lg * 8;
  bf16x8 qa0 = *(const bf16x8*)qrow;
  bf16x8 qa1 = *(const bf16x8*)(qrow + 32);

  f32x4 o[4] = {};
  float mx[4], ls[4] = {0.f, 0.f, 0.f, 0.f};
#pragma unroll
  for (int r = 0; r < 4; ++r) mx[r] = -__builtin_inff();

  const u16* kbase = kh + ((size_t)(head * KVTOT + req * KVP)) * HD;
  const u16* vbase = vt + ((size_t)(head * HD)) * KVTOT + req * KVP;
  const float C = 1.44269504088896340736f;
  u16* Pw = (u16*)&smem[w][0];

  const int kvs = w * 384;
  const int kve = (w == 3) ? ENC : kvs + 384;  // quarters: 384,384,384,348

  for (int kvb = kvs; kvb < kve; kvb += 32) {
    f32x4 s[2];
#pragma unroll
    for (int n = 0; n < 2; ++n) {
      const u16* kr = kbase + (size_t)(kvb + n * 16 + l15) * HD + lg * 8;
      bf16x8 kb0 = *(const bf16x8*)kr;
      bf16x8 kb1 = *(const bf16x8*)(kr + 32);
      f32x4 z = {};
      z = __builtin_amdgcn_mfma_f32_16x16x32_bf16(qa0, kb0, z, 0, 0, 0);
      s[n] = __builtin_amdgcn_mfma_f32_16x16x32_bf16(qa1, kb1, z, 0, 0, 0);
    }
    if (kvb + 32 > ENC) {  // mask kv >= 1500 (pad rows), only last step of wave 3
#pragma unroll
      for (int n = 0; n < 2; ++n)
        if (kvb + n * 16 + l15 >= ENC) {
#pragma unroll
          for (int r = 0; r < 4; ++r) s[n][r] = -__builtin_inff();
        }
    }
#pragma unroll
    for (int r = 0; r < 4; ++r) {
      float v = fmaxf(s[0][r], s[1][r]);
      v = fmaxf(v, __shfl_xor(v, 1));
      v = fmaxf(v, __shfl_xor(v, 2));
      v = fmaxf(v, __shfl_xor(v, 4));
      v = fmaxf(v, __shfl_xor(v, 8));
      float mnew = fmaxf(mx[r], v);
      float sc = exp2f((mx[r] - mnew) * C);
      mx[r] = mnew;
      float p0 = exp2f((s[0][r] - mnew) * C);
      float p1 = exp2f((s[1][r] - mnew) * C);
      ls[r] = ls[r] * sc + p0 + p1;
      o[0][r] *= sc; o[1][r] *= sc; o[2][r] *= sc; o[3][r] *= sc;
      int prow = lg * 4 + r;
      Pw[prow * 32 + l15] = f2bf(p0);
      Pw[prow * 32 + 16 + l15] = f2bf(p1);
    }
    // same-wave LDS transpose: P (C-layout) -> A-frag
    bf16x8 pa = *(const bf16x8*)&Pw[l15 * 32 + lg * 8];
#pragma unroll
    for (int dt = 0; dt < 4; ++dt) {
      const u16* vr = vbase + (size_t)(dt * 16 + l15) * KVTOT + kvb + lg * 8;
      bf16x8 vb = *(const bf16x8*)vr;
      o[dt] = __builtin_amdgcn_mfma_f32_16x16x32_bf16(pa, vb, o[dt], 0, 0, 0);
    }
  }

  // per-wave l reduction across the 16-lane kv groups
#pragma unroll
  for (int r = 0; r < 4; ++r) {
    float v = ls[r];
    v += __shfl_xor(v, 1);
    v += __shfl_xor(v, 2);
    v += __shfl_xor(v, 4);
    v += __shfl_xor(v, 8);
    ls[r] = v;
  }

  // dump partials: o (f32, unnormalized), m, l  (Pbuf no longer needed by this wave)
#pragma unroll
  for (int dt = 0; dt < 4; ++dt)
#pragma unroll
    for (int r = 0; r < 4; ++r)
      smem[w][(lg * 4 + r) * 64 + dt * 16 + l15] = o[dt][r];
  if (l15 == 0) {
#pragma unroll
    for (int r = 0; r < 4; ++r) {
      smem[w][1024 + lg * 4 + r] = mx[r];
      smem[w][1040 + lg * 4 + r] = ls[r];
    }
  }
  __syncthreads();

  // combine: 1024 (row,hd) items over 256 threads
#pragma unroll
  for (int it = 0; it < 4; ++it) {
    int item = threadIdx.x + it * 256;
    int row = item >> 6, hd = item & 63;
    float m0v = smem[0][1024 + row], m1v = smem[1][1024 + row];
    float m2v = smem[2][1024 + row], m3v = smem[3][1024 + row];
    float M = fmaxf(fmaxf(m0v, m1v), fmaxf(m2v, m3v));
    float e0 = exp2f((m0v - M) * C), e1 = exp2f((m1v - M) * C);
    float e2 = exp2f((m2v - M) * C), e3 = exp2f((m3v - M) * C);
    float L = smem[0][1040 + row] * e0 + smem[1][1040 + row] * e1 +
              smem[2][1040 + row] * e2 + smem[3][1040 + row] * e3;
    float O = smem[0][item & 1023] * e0 + smem[1][item & 1023] * e1 +
              smem[2][item & 1023] * e2 + smem[3][item & 1023] * e3;
    int qr = q0 + row;
    if (qr < slen)
      attnb[(size_t)(qstart + qr) * D + head * HD + hd] = f2bf(O / L);
  }
}

extern "C" void kernel_launch(void* const* d_in, const int* in_sizes, int n_in,
                              void* d_out, int out_size, void* d_ws, size_t ws_size,
                              hipStream_t stream) {
  const float* hs  = (const float*)d_in[0];
  const float* chs = (const float*)d_in[1];
  const int*   seq = (const int*)d_in[2];
  const float* Wq  = (const float*)d_in[3];
  const float* bq  = (const float*)d_in[4];
  const float* Wkv = (const float*)d_in[5];
  const float* bkv = (const float*)d_in[6];
  const float* Wo  = (const float*)d_in[7];
  const float* bo  = (const float*)d_in[8];

  char* ws = (char*)d_ws;
  u16* hsb   = (u16*)(ws + 0);          // 1600*1280*2  = 4,096,000
  u16* chsb  = (u16*)(ws + 4096000);    // 6000*1280*2  = 15,360,000
  u16* Wqt   = (u16*)(ws + 19456000);   // 1280*1280*2  = 3,276,800
  u16* Wkvt  = (u16*)(ws + 22732800);   // 2560*1280*2  = 6,553,600
  u16* Wot   = (u16*)(ws + 29286400);   // 3,276,800
  u16* qhb   = (u16*)(ws + 32563200);   // 20*1632*64*2 = 4,177,920
  u16* khb   = (u16*)(ws + 36741120);   // 20*6016*64*2 = 15,400,960
  u16* vtb   = (u16*)(ws + 52142080);   // 15,400,960
  u16* attnb = (u16*)(ws + 67543040);   // 4,096,000  -> total 71,639,040 B

  cvt_kernel<<<2000, 256, 0, stream>>>(hs, hsb, 512000);
  cvt_kernel<<<7500, 256, 0, stream>>>(chs, chsb, 1920000);
  tpose_kernel<<<dim3(40, 40), 256, 0, stream>>>(Wq, Wqt, 1280, 1280);
  tpose_kernel<<<dim3(80, 40), 256, 0, stream>>>(Wkv, Wkvt, 1280, 2560);
  tpose_kernel<<<dim3(40, 40), 256, 0, stream>>>(Wo, Wot, 1280, 1280);

  gemm_kernel<0><<<dim3(10, 13), 256, 0, stream>>>(hsb, Wqt, bq, NQ, qhb, nullptr, nullptr);
  gemm_kernel<1><<<dim3(20, 47), 256, 0, stream>>>(chsb, Wkvt, bkv, NKV, khb, vtb, nullptr);
  attn_kernel<<<dim3(32, 4, 20), 256, 0, stream>>>(qhb, khb, vtb, seq, attnb);
  gemm_kernel<2><<<dim3(10, 13), 256, 0, stream>>>(attnb, Wot, bo, NQ, nullptr, nullptr, (float*)d_out);
}

// Round 3
// 228.955 us; speedup vs baseline: 1.2718x; 1.2481x over previous
//
#include <hip/hip_runtime.h>
#include <stdint.h>

#define AS1 __attribute__((address_space(1)))
#define AS3 __attribute__((address_space(3)))

typedef __bf16 bf16_t;
typedef bf16_t bf16x8 __attribute__((ext_vector_type(8)));
typedef float  f32x4  __attribute__((ext_vector_type(4)));
typedef float  f32x16 __attribute__((ext_vector_type(16)));
typedef unsigned short u16;

constexpr int D     = 1280;
constexpr int H     = 20;
constexpr int HD    = 64;
constexpr int NQ    = 1600;
constexpr int NKV   = 6000;
constexpr int ENC   = 1500;
constexpr int QPAD  = 1632;   // NQ padded so q-row reads past the end stay in-buffer
constexpr int KVP   = 1504;   // per-request kv rows padded to 16 (keeps 16B-aligned frags)
constexpr int KVTOT = 4 * KVP;

__device__ __forceinline__ u16 f2bf(float f) {
  union { float f; uint32_t u; } x; x.f = f;
  uint32_t r = (x.u + 0x7fffu + ((x.u >> 16) & 1u)) >> 16;  // RNE
  return (u16)r;
}

__device__ __forceinline__ void gload16(const void* g, void* l) {
  __builtin_amdgcn_global_load_lds((AS1 void*)g, (AS3 void*)l, 16, 0, 0);
}

// ---------------- fp32 -> bf16 elementwise (vectorized) ----------------
__global__ __launch_bounds__(256)
void cvt_kernel(const float* __restrict__ in, u16* __restrict__ out, int n4) {
  int i = blockIdx.x * 256 + threadIdx.x;
  if (i >= n4) return;
  float4 v = ((const float4*)in)[i];
  ushort4 o;
  o.x = f2bf(v.x); o.y = f2bf(v.y); o.z = f2bf(v.z); o.w = f2bf(v.w);
  ((ushort4*)out)[i] = o;
}

// ---------------- fp32 [R][C] -> bf16 [C][R] tiled transpose ----------------
__global__ __launch_bounds__(256)
void tpose_kernel(const float* __restrict__ in, u16* __restrict__ out, int R, int C) {
  __shared__ u16 tile[32][33];
  int bc = blockIdx.x * 32, br = blockIdx.y * 32;
  int tx = threadIdx.x & 31, ty = threadIdx.x >> 5;  // 32 x 8
#pragma unroll
  for (int i = 0; i < 32; i += 8)
    tile[ty + i][tx] = f2bf(in[(size_t)(br + ty + i) * C + bc + tx]);
  __syncthreads();
#pragma unroll
  for (int i = 0; i < 32; i += 8)
    out[(size_t)(bc + ty + i) * R + br + tx] = tile[tx][ty + i];
}

// ---------------- bf16 GEMM: C[M,N] = A[M,1280] @ Bt[N,1280]^T + bias ----------------
// MODE 0: Q-proj  -> qh[h][row][hd] = (c+b)*0.125          (bf16)
// MODE 1: KV-proj -> kh[h][req*KVP+loc][hd] / vt[h][hd][req*KVP+loc]  (bf16)
// MODE 2: O-proj  -> outF[row*1280+col] = c+b               (fp32)
template <int MODE>
__global__ __launch_bounds__(256)
void gemm_kernel(const u16* __restrict__ A, const u16* __restrict__ Bt,
                 const float* __restrict__ bias, int M,
                 u16* __restrict__ outA, u16* __restrict__ outB, float* __restrict__ outF) {
  __shared__ __align__(16) u16 As[128 * 64];
  __shared__ __align__(16) u16 Bs[128 * 64];
  const int tid = threadIdx.x;
  const int lane = tid & 63, l15 = lane & 15, lg = lane >> 4;
  const int w = tid >> 6, wr = w >> 1, wc = w & 1;
  const int m0 = blockIdx.y * 128, n0 = blockIdx.x * 128;

  f32x4 acc[4][4] = {};

  for (int k0 = 0; k0 < D; k0 += 64) {
#pragma unroll
    for (int p = 0; p < 4; ++p) {
      int off = p * 4096 + tid * 16;
      int lg_off = off ^ (((off >> 7) & 7) << 4);
      int row = lg_off >> 7, kb = lg_off & 127;
      int gr = m0 + row; gr = gr < M ? gr : M - 1;  // clamp M-tail
      gload16((const char*)A + ((size_t)gr * D + k0) * 2 + kb, (char*)As + off);
    }
#pragma unroll
    for (int p = 0; p < 4; ++p) {
      int off = p * 4096 + tid * 16;
      int lg_off = off ^ (((off >> 7) & 7) << 4);
      int row = lg_off >> 7, kb = lg_off & 127;
      int gr = n0 + row;  // N is always a multiple of 128
      gload16((const char*)Bt + ((size_t)gr * D + k0) * 2 + kb, (char*)Bs + off);
    }
    __syncthreads();
#pragma unroll
    for (int kk = 0; kk < 2; ++kk) {
      const int kbyte = kk * 64 + lg * 16;
      bf16x8 af[4], bfr[4];
#pragma unroll
      for (int m = 0; m < 4; ++m) {
        int row = wr * 64 + m * 16 + l15;
        int addr = ((row << 7) + kbyte) ^ ((row & 7) << 4);
        af[m] = *(const bf16x8*)((const char*)As + addr);
      }
#pragma unroll
      for (int n = 0; n < 4; ++n) {
        int row = wc * 64 + n * 16 + l15;
        int addr = ((row << 7) + kbyte) ^ ((row & 7) << 4);
        bfr[n] = *(const bf16x8*)((const char*)Bs + addr);
      }
#pragma unroll
      for (int m = 0; m < 4; ++m)
#pragma unroll
        for (int n = 0; n < 4; ++n)
          acc[m][n] = __builtin_amdgcn_mfma_f32_16x16x32_bf16(af[m], bfr[n], acc[m][n], 0, 0, 0);
    }
    __syncthreads();
  }

#pragma unroll
  for (int m = 0; m < 4; ++m)
#pragma unroll
    for (int n = 0; n < 4; ++n) {
      int col = n0 + wc * 64 + n * 16 + l15;
      float bv = bias[col];
#pragma unroll
      for (int r = 0; r < 4; ++r) {
        int row = m0 + wr * 64 + m * 16 + lg * 4 + r;
        if (row >= M) continue;
        float v = acc[m][n][r] + bv;
        if (MODE == 0) {
          v *= 0.125f;  // HD^-0.5
          int h = col >> 6, hd = col & 63;
          outA[((size_t)(h * QPAD + row)) * HD + hd] = f2bf(v);
        } else if (MODE == 1) {
          int req = row / ENC, loc = row - req * ENC;
          int rr = req * KVP + loc;
          if (col < D) {
            int h = col >> 6, hd = col & 63;
            outA[((size_t)(h * KVTOT + rr)) * HD + hd] = f2bf(v);
          } else {
            int c2 = col - D, h = c2 >> 6, hd = c2 & 63;
            outB[((size_t)(h * HD + hd)) * KVTOT + rr] = f2bf(v);
          }
        } else {
          outF[(size_t)row * D + col] = v;
        }
      }
    }
}

// ---------------- flash attention, swapped-QK^T 32x32, in-register softmax ----------------
// Block = (q32-tile, req, head); 4 waves kv-split (384/384/384/348).
// S^T = mfma_32x32x16(A=K, B=Q): lane holds 16 kv-scores of ONE q column ->
// softmax reduction is in-register (+1 cross-half shfl). P repacked to PV's
// B-operand with 8 pack + 8 shfl_xor(32) + 8 selects. O^T accumulated in regs.
__global__ __launch_bounds__(256)
void attn_kernel(const u16* __restrict__ qh, const u16* __restrict__ kh,
                 const u16* __restrict__ vt, const int* __restrict__ seq,
                 u16* __restrict__ attnb) {
  // per-wave: O^T at [d*33+q] (2112 floats, pad-33 kills bank conflicts both ways),
  // m at [2112+q], l at [2144+q]
  __shared__ __align__(16) float smem[4][2176];
  const int lane = threadIdx.x & 63;
  const int l31 = lane & 31, h5 = lane >> 5;
  const int w = threadIdx.x >> 6;
  const int head = blockIdx.z, req = blockIdx.y;
  int s0 = seq[0], s1 = seq[1], s2 = seq[2];
  int qstart = (req > 0 ? s0 : 0) + (req > 1 ? s1 : 0) + (req > 2 ? s2 : 0);
  int slen = seq[req];
  int q0 = blockIdx.x * 32;
  if (q0 >= slen) return;  // block-uniform: safe w.r.t. __syncthreads

  // Q B-frags (B[k=hd][col=q]: col=lane&31, k=(lane>>5)*8+e), 4 k-slots of 16
  const u16* qrow = qh + ((size_t)(head * QPAD + qstart + q0 + l31)) * HD + h5 * 8;
  bf16x8 qb[4];
#pragma unroll
  for (int ks = 0; ks < 4; ++ks) qb[ks] = *(const bf16x8*)(qrow + ks * 16);

  const u16* kbase = kh + ((size_t)(head * KVTOT + req * KVP)) * HD;
  const u16* vbase = vt + ((size_t)(head * HD)) * KVTOT + req * KVP;
  const float C = 1.44269504088896340736f;

  f32x16 o0 = {}, o1 = {};
  float mx = -__builtin_inff(), ls = 0.f;

  const int kvs = w * 384;
  const int kve = (w == 3) ? ENC : kvs + 384;  // quarters: 384,384,384,348

  for (int kvb = kvs; kvb < kve; kvb += 32) {
    // K A-frags (A[row=kv][k=hd]): 4 slots; V^T A-frags: 2 d-tiles x 2 kv-slots
    const u16* kr = kbase + (size_t)(kvb + l31) * HD + h5 * 8;
    bf16x8 ka[4];
#pragma unroll
    for (int ks = 0; ks < 4; ++ks) ka[ks] = *(const bf16x8*)(kr + ks * 16);
    bf16x8 va[2][2];
#pragma unroll
    for (int dt = 0; dt < 2; ++dt)
#pragma unroll
      for (int ks = 0; ks < 2; ++ks)
        va[dt][ks] = *(const bf16x8*)(vbase + (size_t)(dt * 32 + l31) * KVTOT + kvb + ks * 16 + h5 * 8);

    // S^T[kv][q] over hd: lane q=l31 holds kv = (r&3)+4*h5+8*(r>>2), r=0..15
    f32x16 sa = {};
#pragma unroll
    for (int ks = 0; ks < 4; ++ks)
      sa = __builtin_amdgcn_mfma_f32_32x32x16_bf16(ka[ks], qb[ks], sa, 0, 0, 0);

    if (kvb + 32 > ENC) {  // mask pad rows (only last step of wave 3)
#pragma unroll
      for (int r = 0; r < 16; ++r) {
        int kvr = (r & 3) + 4 * h5 + 8 * (r >> 2);
        sa[r] = (kvb + kvr >= ENC) ? -__builtin_inff() : sa[r];
      }
    }

    // in-register row max (per q), one cross-half merge
    float tm = sa[0];
#pragma unroll
    for (int r = 1; r < 16; ++r) tm = fmaxf(tm, sa[r]);
    tm = fmaxf(tm, __shfl_xor(tm, 32));
    float mnew = fmaxf(mx, tm);
    float sc = exp2f((mx - mnew) * C);
    mx = mnew;
    float psum = 0.f;
#pragma unroll
    for (int r = 0; r < 16; ++r) { sa[r] = exp2f((sa[r] - mnew) * C); psum += sa[r]; }
    ls = ls * sc + psum;
    o0 *= sc; o1 *= sc;

    // pack P to bf16 words (kv pairs), exchange halves, assemble B-frags
    uint32_t a[8], x[8];
#pragma unroll
    for (int i = 0; i < 8; ++i)
      a[i] = (uint32_t)f2bf(sa[2 * i]) | ((uint32_t)f2bf(sa[2 * i + 1]) << 16);
#pragma unroll
    for (int i = 0; i < 8; ++i) x[i] = (uint32_t)__shfl_xor((int)a[i], 32);
    union { uint32_t w4[4]; bf16x8 v; } pb0, pb1;
    pb0.w4[0] = h5 ? x[2] : a[0]; pb0.w4[1] = h5 ? x[3] : a[1];
    pb0.w4[2] = h5 ? a[2] : x[0]; pb0.w4[3] = h5 ? a[3] : x[1];
    pb1.w4[0] = h5 ? x[6] : a[4]; pb1.w4[1] = h5 ? x[7] : a[5];
    pb1.w4[2] = h5 ? a[6] : x[4]; pb1.w4[3] = h5 ? a[7] : x[5];

    // O^T[d][q] += V^T[d][kv] * P^T[kv][q]
    o0 = __builtin_amdgcn_mfma_f32_32x32x16_bf16(va[0][0], pb0.v, o0, 0, 0, 0);
    o0 = __builtin_amdgcn_mfma_f32_32x32x16_bf16(va[0][1], pb1.v, o0, 0, 0, 0);
    o1 = __builtin_amdgcn_mfma_f32_32x32x16_bf16(va[1][0], pb0.v, o1, 0, 0, 0);
    o1 = __builtin_amdgcn_mfma_f32_32x32x16_bf16(va[1][1], pb1.v, o1, 0, 0, 0);
  }

  ls += __shfl_xor(ls, 32);  // total l over both halves

  // dump partials: O^T, m, l
#pragma unroll
  for (int r = 0; r < 16; ++r) {
    int drow = (r & 3) + 8 * (r >> 2) + 4 * h5;
    smem[w][drow * 33 + l31] = o0[r];
    smem[w][(drow + 32) * 33 + l31] = o1[r];
  }
  if (h5 == 0) {
    smem[w][2112 + l31] = mx;
    smem[w][2144 + l31] = ls;
  }
  __syncthreads();

  // combine: 2048 (q,d) items over 256 threads
#pragma unroll
  for (int it = 0; it < 8; ++it) {
    int item = threadIdx.x + it * 256;
    int q = item >> 6, d = item & 63;
    float m0v = smem[0][2112 + q], m1v = smem[1][2112 + q];
    float m2v = smem[2][2112 + q], m3v = smem[3][2112 + q];
    float M = fmaxf(fmaxf(m0v, m1v), fmaxf(m2v, m3v));
    float e0 = exp2f((m0v - M) * C), e1 = exp2f((m1v - M) * C);
    float e2 = exp2f((m2v - M) * C), e3 = exp2f((m3v - M) * C);
    float L = smem[0][2144 + q] * e0 + smem[1][2144 + q] * e1 +
              smem[2][2144 + q] * e2 + smem[3][2144 + q] * e3;
    float O = smem[0][d * 33 + q] * e0 + smem[1][d * 33 + q] * e1 +
              smem[2][d * 33 + q] * e2 + smem[3][d * 33 + q] * e3;
    int qr = q0 + q;
    if (qr < slen)
      attnb[(size_t)(qstart + qr) * D + head * HD + d] = f2bf(O / L);
  }
}

extern "C" void kernel_launch(void* const* d_in, const int* in_sizes, int n_in,
                              void* d_out, int out_size, void* d_ws, size_t ws_size,
                              hipStream_t stream) {
  const float* hs  = (const float*)d_in[0];
  const float* chs = (const float*)d_in[1];
  const int*   seq = (const int*)d_in[2];
  const float* Wq  = (const float*)d_in[3];
  const float* bq  = (const float*)d_in[4];
  const float* Wkv = (const float*)d_in[5];
  const float* bkv = (const float*)d_in[6];
  const float* Wo  = (const float*)d_in[7];
  const float* bo  = (const float*)d_in[8];

  char* ws = (char*)d_ws;
  u16* hsb   = (u16*)(ws + 0);          // 1600*1280*2  = 4,096,000
  u16* chsb  = (u16*)(ws + 4096000);    // 6000*1280*2  = 15,360,000
  u16* Wqt   = (u16*)(ws + 19456000);   // 1280*1280*2  = 3,276,800
  u16* Wkvt  = (u16*)(ws + 22732800);   // 2560*1280*2  = 6,553,600
  u16* Wot   = (u16*)(ws + 29286400);   // 3,276,800
  u16* qhb   = (u16*)(ws + 32563200);   // 20*1632*64*2 = 4,177,920
  u16* khb   = (u16*)(ws + 36741120);   // 20*6016*64*2 = 15,400,960
  u16* vtb   = (u16*)(ws + 52142080);   // 15,400,960
  u16* attnb = (u16*)(ws + 67543040);   // 4,096,000  -> total 71,639,040 B

  cvt_kernel<<<2000, 256, 0, stream>>>(hs, hsb, 512000);
  cvt_kernel<<<7500, 256, 0, stream>>>(chs, chsb, 1920000);
  tpose_kernel<<<dim3(40, 40), 256, 0, stream>>>(Wq, Wqt, 1280, 1280);
  tpose_kernel<<<dim3(80, 40), 256, 0, stream>>>(Wkv, Wkvt, 1280, 2560);
  tpose_kernel<<<dim3(40, 40), 256, 0, stream>>>(Wo, Wot, 1280, 1280);

  gemm_kernel<0><<<dim3(10, 13), 256, 0, stream>>>(hsb, Wqt, bq, NQ, qhb, nullptr, nullptr);
  gemm_kernel<1><<<dim3(20, 47), 256, 0, stream>>>(chsb, Wkvt, bkv, NKV, khb, vtb, nullptr);
  attn_kernel<<<dim3(16, 4, 20), 256, 0, stream>>>(qhb, khb, vtb, seq, attnb);
  gemm_kernel<2><<<dim3(10, 13), 256, 0, stream>>>(attnb, Wot, bo, NQ, nullptr, nullptr, (float*)d_out);
}

// Round 4
// 211.074 us; speedup vs baseline: 1.3795x; 1.0847x over previous
//
#include <hip/hip_runtime.h>
#include <stdint.h>

#define AS1 __attribute__((address_space(1)))
#define AS3 __attribute__((address_space(3)))

typedef __bf16 bf16_t;
typedef bf16_t bf16x8 __attribute__((ext_vector_type(8)));
typedef float  f32x4  __attribute__((ext_vector_type(4)));
typedef float  f32x16 __attribute__((ext_vector_type(16)));
typedef unsigned short u16;

constexpr int D     = 1280;
constexpr int H     = 20;
constexpr int HD    = 64;
constexpr int NQ    = 1600;
constexpr int NKV   = 6000;
constexpr int ENC   = 1500;
constexpr int QPAD  = 1632;   // NQ padded so q-row reads past the end stay in-buffer
constexpr int KVP   = 1504;   // per-request kv rows padded to 16 (keeps 16B-aligned frags)
constexpr int KVTOT = 4 * KVP;

__device__ __forceinline__ u16 f2bf(float f) {
  union { float f; uint32_t u; } x; x.f = f;
  uint32_t r = (x.u + 0x7fffu + ((x.u >> 16) & 1u)) >> 16;  // RNE
  return (u16)r;
}

__device__ __forceinline__ void gload16(const void* g, void* l) {
  __builtin_amdgcn_global_load_lds((AS1 void*)g, (AS3 void*)l, 16, 0, 0);
}

// ---------------- fp32 -> bf16 elementwise (vectorized) ----------------
__global__ __launch_bounds__(256)
void cvt_kernel(const float* __restrict__ in, u16* __restrict__ out, int n4) {
  int i = blockIdx.x * 256 + threadIdx.x;
  if (i >= n4) return;
  float4 v = ((const float4*)in)[i];
  ushort4 o;
  o.x = f2bf(v.x); o.y = f2bf(v.y); o.z = f2bf(v.z); o.w = f2bf(v.w);
  ((ushort4*)out)[i] = o;
}

// ---------------- fp32 [R][C] -> bf16 [C][R] tiled transpose ----------------
__global__ __launch_bounds__(256)
void tpose_kernel(const float* __restrict__ in, u16* __restrict__ out, int R, int C) {
  __shared__ u16 tile[32][33];
  int bc = blockIdx.x * 32, br = blockIdx.y * 32;
  int tx = threadIdx.x & 31, ty = threadIdx.x >> 5;  // 32 x 8
#pragma unroll
  for (int i = 0; i < 32; i += 8)
    tile[ty + i][tx] = f2bf(in[(size_t)(br + ty + i) * C + bc + tx]);
  __syncthreads();
#pragma unroll
  for (int i = 0; i < 32; i += 8)
    out[(size_t)(bc + ty + i) * R + br + tx] = tile[tx][ty + i];
}

// ---------------- bf16 GEMM: C[M,N] = A[M,1280] @ Bt[N,1280]^T + bias ----------------
// 1D grid + bijective XCD swizzle (m204). NX = tiles along N.
// MODE 0: Q-proj  -> qh[h][row][hd] = (c+b)*0.125          (bf16)
// MODE 1: KV-proj -> kh[h][req*KVP+loc][hd]  (K blocks, n0<1280)
//                    vt[h][hd][req*KVP+loc]  (V blocks, n0>=1280: computed as C^T
//                    via swapped MFMA operands so vt stores are coalesced)
// MODE 2: O-proj  -> outF[row*1280+col] = c+b               (fp32)
template <int MODE, int NX>
__global__ __launch_bounds__(256)
void gemm_kernel(const u16* __restrict__ A, const u16* __restrict__ Bt,
                 const float* __restrict__ bias, int M,
                 u16* __restrict__ outA, u16* __restrict__ outB, float* __restrict__ outF) {
  __shared__ __align__(16) u16 As[128 * 64];
  __shared__ __align__(16) u16 Bs[128 * 64];
  const int tid = threadIdx.x;
  const int lane = tid & 63, l15 = lane & 15, lg = lane >> 4;
  const int w = tid >> 6, wr = w >> 1, wc = w & 1;

  // bijective XCD-aware block remap (m204): orig%8 = dispatch XCD
  const int nwg = gridDim.x;
  const int q8 = nwg >> 3, r8 = nwg & 7;
  const int xcd = blockIdx.x & 7, pos = blockIdx.x >> 3;
  const int wg = (xcd < r8 ? xcd * (q8 + 1) : r8 * (q8 + 1) + (xcd - r8) * q8) + pos;
  const int m0 = (wg / NX) * 128, n0 = (wg % NX) * 128;

  const bool vside = (MODE == 1) && (n0 >= D);

  f32x4 acc[4][4] = {};

  for (int k0 = 0; k0 < D; k0 += 64) {
#pragma unroll
    for (int p = 0; p < 4; ++p) {
      int off = p * 4096 + tid * 16;
      int lg_off = off ^ (((off >> 7) & 7) << 4);
      int row = lg_off >> 7, kb = lg_off & 127;
      int gr = m0 + row; gr = gr < M ? gr : M - 1;  // clamp M-tail
      gload16((const char*)A + ((size_t)gr * D + k0) * 2 + kb, (char*)As + off);
    }
#pragma unroll
    for (int p = 0; p < 4; ++p) {
      int off = p * 4096 + tid * 16;
      int lg_off = off ^ (((off >> 7) & 7) << 4);
      int row = lg_off >> 7, kb = lg_off & 127;
      int gr = n0 + row;  // N is always a multiple of 128
      gload16((const char*)Bt + ((size_t)gr * D + k0) * 2 + kb, (char*)Bs + off);
    }
    __syncthreads();
#pragma unroll
    for (int kk = 0; kk < 2; ++kk) {
      const int kbyte = kk * 64 + lg * 16;
      bf16x8 af[4], bfr[4];
#pragma unroll
      for (int m = 0; m < 4; ++m) {
        int row = wr * 64 + m * 16 + l15;
        int addr = ((row << 7) + kbyte) ^ ((row & 7) << 4);
        af[m] = *(const bf16x8*)((const char*)As + addr);
      }
#pragma unroll
      for (int n = 0; n < 4; ++n) {
        int row = wc * 64 + n * 16 + l15;
        int addr = ((row << 7) + kbyte) ^ ((row & 7) << 4);
        bfr[n] = *(const bf16x8*)((const char*)Bs + addr);
      }
      if (!vside) {
#pragma unroll
        for (int m = 0; m < 4; ++m)
#pragma unroll
          for (int n = 0; n < 4; ++n)
            acc[m][n] = __builtin_amdgcn_mfma_f32_16x16x32_bf16(af[m], bfr[n], acc[m][n], 0, 0, 0);
      } else {
        // C^T: D[n][m] — lane dim (col) becomes the M/kv index
#pragma unroll
        for (int m = 0; m < 4; ++m)
#pragma unroll
          for (int n = 0; n < 4; ++n)
            acc[m][n] = __builtin_amdgcn_mfma_f32_16x16x32_bf16(bfr[n], af[m], acc[m][n], 0, 0, 0);
      }
    }
    __syncthreads();
  }

  if (!vside) {
    // C/D layout: col = n-idx = lane&15, row = m-idx = (lane>>4)*4 + reg
#pragma unroll
    for (int m = 0; m < 4; ++m)
#pragma unroll
      for (int n = 0; n < 4; ++n) {
        int col = n0 + wc * 64 + n * 16 + l15;
        float bv = bias[col];
#pragma unroll
        for (int r = 0; r < 4; ++r) {
          int row = m0 + wr * 64 + m * 16 + lg * 4 + r;
          if (row >= M) continue;
          float v = acc[m][n][r] + bv;
          if (MODE == 0) {
            v *= 0.125f;  // HD^-0.5
            int h = col >> 6, hd = col & 63;
            outA[((size_t)(h * QPAD + row)) * HD + hd] = f2bf(v);
          } else if (MODE == 1) {
            int req = row / ENC, loc = row - req * ENC;
            int rr = req * KVP + loc;
            int h = col >> 6, hd = col & 63;
            outA[((size_t)(h * KVTOT + rr)) * HD + hd] = f2bf(v);
          } else {
            outF[(size_t)row * D + col] = v;
          }
        }
      }
  } else {
    // C^T: lane&15 = kv-row offset; (lane>>4)*4+reg = output-col offset
    float bvv[4][4];
#pragma unroll
    for (int n = 0; n < 4; ++n)
#pragma unroll
      for (int r = 0; r < 4; ++r)
        bvv[n][r] = bias[n0 + wc * 64 + n * 16 + lg * 4 + r];
#pragma unroll
    for (int m = 0; m < 4; ++m) {
      int gm = m0 + wr * 64 + m * 16 + l15;  // kv row (per-lane)
      int req = gm / ENC, loc = gm - req * ENC;
      int rr = req * KVP + loc;
      bool ok = gm < M;
#pragma unroll
      for (int n = 0; n < 4; ++n)
#pragma unroll
        for (int r = 0; r < 4; ++r) {
          if (!ok) continue;
          int c2 = n0 + wc * 64 + n * 16 + lg * 4 + r - D;
          int h = c2 >> 6, hd = c2 & 63;
          outB[((size_t)(h * HD + hd)) * KVTOT + rr] = f2bf(acc[m][n][r] + bvv[n][r]);
        }
    }
  }
}

// ---------------- flash attention, swapped-QK^T 32x32, in-register softmax ----------------
// Block = (q32-tile, req, head); 4 waves kv-split (384/384/384/348).
// S^T = mfma_32x32x16(A=K, B=Q): lane holds 16 kv-scores of ONE q column ->
// softmax reduction is in-register (+1 cross-half shfl). P repacked to PV's
// B-operand with 8 pack + 8 shfl_xor(32) + 8 selects. O^T accumulated in regs.
__global__ __launch_bounds__(256)
void attn_kernel(const u16* __restrict__ qh, const u16* __restrict__ kh,
                 const u16* __restrict__ vt, const int* __restrict__ seq,
                 u16* __restrict__ attnb) {
  // per-wave: O^T at [d*33+q] (2112 floats, pad-33 kills bank conflicts both ways),
  // m at [2112+q], l at [2144+q]
  __shared__ __align__(16) float smem[4][2176];
  const int lane = threadIdx.x & 63;
  const int l31 = lane & 31, h5 = lane >> 5;
  const int w = threadIdx.x >> 6;
  const int head = blockIdx.z, req = blockIdx.y;
  int s0 = seq[0], s1 = seq[1], s2 = seq[2];
  int qstart = (req > 0 ? s0 : 0) + (req > 1 ? s1 : 0) + (req > 2 ? s2 : 0);
  int slen = seq[req];
  int q0 = blockIdx.x * 32;
  if (q0 >= slen) return;  // block-uniform: safe w.r.t. __syncthreads

  // Q B-frags (B[k=hd][col=q]: col=lane&31, k=(lane>>5)*8+e), 4 k-slots of 16
  const u16* qrow = qh + ((size_t)(head * QPAD + qstart + q0 + l31)) * HD + h5 * 8;
  bf16x8 qb[4];
#pragma unroll
  for (int ks = 0; ks < 4; ++ks) qb[ks] = *(const bf16x8*)(qrow + ks * 16);

  const u16* kbase = kh + ((size_t)(head * KVTOT + req * KVP)) * HD;
  const u16* vbase = vt + ((size_t)(head * HD)) * KVTOT + req * KVP;
  const float C = 1.44269504088896340736f;

  f32x16 o0 = {}, o1 = {};
  float mx = -__builtin_inff(), ls = 0.f;

  const int kvs = w * 384;
  const int kve = (w == 3) ? ENC : kvs + 384;  // quarters: 384,384,384,348

  for (int kvb = kvs; kvb < kve; kvb += 32) {
    // K A-frags (A[row=kv][k=hd]): 4 slots; V^T A-frags: 2 d-tiles x 2 kv-slots
    const u16* kr = kbase + (size_t)(kvb + l31) * HD + h5 * 8;
    bf16x8 ka[4];
#pragma unroll
    for (int ks = 0; ks < 4; ++ks) ka[ks] = *(const bf16x8*)(kr + ks * 16);
    bf16x8 va[2][2];
#pragma unroll
    for (int dt = 0; dt < 2; ++dt)
#pragma unroll
      for (int ks = 0; ks < 2; ++ks)
        va[dt][ks] = *(const bf16x8*)(vbase + (size_t)(dt * 32 + l31) * KVTOT + kvb + ks * 16 + h5 * 8);

    // S^T[kv][q] over hd: lane q=l31 holds kv = (r&3)+4*h5+8*(r>>2), r=0..15
    f32x16 sa = {};
#pragma unroll
    for (int ks = 0; ks < 4; ++ks)
      sa = __builtin_amdgcn_mfma_f32_32x32x16_bf16(ka[ks], qb[ks], sa, 0, 0, 0);

    if (kvb + 32 > ENC) {  // mask pad rows (only last step of wave 3)
#pragma unroll
      for (int r = 0; r < 16; ++r) {
        int kvr = (r & 3) + 4 * h5 + 8 * (r >> 2);
        sa[r] = (kvb + kvr >= ENC) ? -__builtin_inff() : sa[r];
      }
    }

    // in-register row max (per q), one cross-half merge
    float tm = sa[0];
#pragma unroll
    for (int r = 1; r < 16; ++r) tm = fmaxf(tm, sa[r]);
    tm = fmaxf(tm, __shfl_xor(tm, 32));
    float mnew = fmaxf(mx, tm);
    float sc = exp2f((mx - mnew) * C);
    mx = mnew;
    float psum = 0.f;
#pragma unroll
    for (int r = 0; r < 16; ++r) { sa[r] = exp2f((sa[r] - mnew) * C); psum += sa[r]; }
    ls = ls * sc + psum;
    o0 *= sc; o1 *= sc;

    // pack P to bf16 words (kv pairs), exchange halves, assemble B-frags
    uint32_t a[8], x[8];
#pragma unroll
    for (int i = 0; i < 8; ++i)
      a[i] = (uint32_t)f2bf(sa[2 * i]) | ((uint32_t)f2bf(sa[2 * i + 1]) << 16);
#pragma unroll
    for (int i = 0; i < 8; ++i) x[i] = (uint32_t)__shfl_xor((int)a[i], 32);
    union { uint32_t w4[4]; bf16x8 v; } pb0, pb1;
    pb0.w4[0] = h5 ? x[2] : a[0]; pb0.w4[1] = h5 ? x[3] : a[1];
    pb0.w4[2] = h5 ? a[2] : x[0]; pb0.w4[3] = h5 ? a[3] : x[1];
    pb1.w4[0] = h5 ? x[6] : a[4]; pb1.w4[1] = h5 ? x[7] : a[5];
    pb1.w4[2] = h5 ? a[6] : x[4]; pb1.w4[3] = h5 ? a[7] : x[5];

    // O^T[d][q] += V^T[d][kv] * P^T[kv][q]
    o0 = __builtin_amdgcn_mfma_f32_32x32x16_bf16(va[0][0], pb0.v, o0, 0, 0, 0);
    o0 = __builtin_amdgcn_mfma_f32_32x32x16_bf16(va[0][1], pb1.v, o0, 0, 0, 0);
    o1 = __builtin_amdgcn_mfma_f32_32x32x16_bf16(va[1][0], pb0.v, o1, 0, 0, 0);
    o1 = __builtin_amdgcn_mfma_f32_32x32x16_bf16(va[1][1], pb1.v, o1, 0, 0, 0);
  }

  ls += __shfl_xor(ls, 32);  // total l over both halves

  // dump partials: O^T, m, l
#pragma unroll
  for (int r = 0; r < 16; ++r) {
    int drow = (r & 3) + 8 * (r >> 2) + 4 * h5;
    smem[w][drow * 33 + l31] = o0[r];
    smem[w][(drow + 32) * 33 + l31] = o1[r];
  }
  if (h5 == 0) {
    smem[w][2112 + l31] = mx;
    smem[w][2144 + l31] = ls;
  }
  __syncthreads();

  // combine: 2048 (q,d) items over 256 threads
#pragma unroll
  for (int it = 0; it < 8; ++it) {
    int item = threadIdx.x + it * 256;
    int q = item >> 6, d = item & 63;
    float m0v = smem[0][2112 + q], m1v = smem[1][2112 + q];
    float m2v = smem[2][2112 + q], m3v = smem[3][2112 + q];
    float M = fmaxf(fmaxf(m0v, m1v), fmaxf(m2v, m3v));
    float e0 = exp2f((m0v - M) * C), e1 = exp2f((m1v - M) * C);
    float e2 = exp2f((m2v - M) * C), e3 = exp2f((m3v - M) * C);
    float L = smem[0][2144 + q] * e0 + smem[1][2144 + q] * e1 +
              smem[2][2144 + q] * e2 + smem[3][2144 + q] * e3;
    float O = smem[0][d * 33 + q] * e0 + smem[1][d * 33 + q] * e1 +
              smem[2][d * 33 + q] * e2 + smem[3][d * 33 + q] * e3;
    int qr = q0 + q;
    if (qr < slen)
      attnb[(size_t)(qstart + qr) * D + head * HD + d] = f2bf(O / L);
  }
}

extern "C" void kernel_launch(void* const* d_in, const int* in_sizes, int n_in,
                              void* d_out, int out_size, void* d_ws, size_t ws_size,
                              hipStream_t stream) {
  const float* hs  = (const float*)d_in[0];
  const float* chs = (const float*)d_in[1];
  const int*   seq = (const int*)d_in[2];
  const float* Wq  = (const float*)d_in[3];
  const float* bq  = (const float*)d_in[4];
  const float* Wkv = (const float*)d_in[5];
  const float* bkv = (const float*)d_in[6];
  const float* Wo  = (const float*)d_in[7];
  const float* bo  = (const float*)d_in[8];

  char* ws = (char*)d_ws;
  u16* hsb   = (u16*)(ws + 0);          // 1600*1280*2  = 4,096,000
  u16* chsb  = (u16*)(ws + 4096000);    // 6000*1280*2  = 15,360,000
  u16* Wqt   = (u16*)(ws + 19456000);   // 1280*1280*2  = 3,276,800
  u16* Wkvt  = (u16*)(ws + 22732800);   // 2560*1280*2  = 6,553,600
  u16* Wot   = (u16*)(ws + 29286400);   // 3,276,800
  u16* qhb   = (u16*)(ws + 32563200);   // 20*1632*64*2 = 4,177,920
  u16* khb   = (u16*)(ws + 36741120);   // 20*6016*64*2 = 15,400,960
  u16* vtb   = (u16*)(ws + 52142080);   // 15,400,960
  u16* attnb = (u16*)(ws + 67543040);   // 4,096,000  -> total 71,639,040 B

  cvt_kernel<<<2000, 256, 0, stream>>>(hs, hsb, 512000);
  cvt_kernel<<<7500, 256, 0, stream>>>(chs, chsb, 1920000);
  tpose_kernel<<<dim3(40, 40), 256, 0, stream>>>(Wq, Wqt, 1280, 1280);
  tpose_kernel<<<dim3(80, 40), 256, 0, stream>>>(Wkv, Wkvt, 1280, 2560);
  tpose_kernel<<<dim3(40, 40), 256, 0, stream>>>(Wo, Wot, 1280, 1280);

  gemm_kernel<0, 10><<<130, 256, 0, stream>>>(hsb, Wqt, bq, NQ, qhb, nullptr, nullptr);
  gemm_kernel<1, 20><<<940, 256, 0, stream>>>(chsb, Wkvt, bkv, NKV, khb, vtb, nullptr);
  attn_kernel<<<dim3(16, 4, 20), 256, 0, stream>>>(qhb, khb, vtb, seq, attnb);
  gemm_kernel<2, 10><<<130, 256, 0, stream>>>(attnb, Wot, bo, NQ, nullptr, nullptr, (float*)d_out);
}